// Round 5
// baseline (617.792 us; speedup 1.0000x reference)
//
#include <hip/hip_runtime.h>
#include <math.h>

// B=8, N=40962, D=40, H=512, D_DYN=32, 4 steps, dt=0.1
constexpr int BB   = 8;
constexpr int NN   = 40962;
constexpr int DDIM = 40;
constexpr int HH   = 512;
constexpr int DDYN = 32;
constexpr float STEPSZ = 0.1f;

constexpr int TM   = 64;      // nodes per block
constexpr int NTHR = 1024;    // 16 waves
constexpr int ZS   = 168;     // z row stride (bf16): 336B -> conflict-free b128 reads

constexpr size_t X_ELEMS = (size_t)BB * NN * DDIM;
constexpr size_t X_BYTES = X_ELEMS * 4;
constexpr int W1P_ELEMS = 32 * 5 * 64 * 8;   // bf16 A-frags [mt][kk][lane][j]
constexpr int W2P_BYTES = 2 * 16 * 64 * 8;   // fp8 A-frags  [jt][kk][lane][j]

// LDS: z [64][168] bf16 = 21504 | h [64][512] fp8 = 32768 | xself [64][40] f32 = 10240
// stg (8 waves x 64 lanes x 16B = 8192) overlays z (dead after barrier 2).
// Total 64512 <= 64KiB -> 2 blocks/CU.
constexpr int Z_BYTES = TM * ZS * 2;             // 21504
constexpr int H_OFF   = Z_BYTES;                 // 21504
constexpr int H_BYTES = TM * HH;                 // 32768
constexpr int XS_OFF  = H_OFF + H_BYTES;         // 54272
constexpr int LDS_TOT = XS_OFF + TM * DDIM * 4;  // 64512

typedef __attribute__((ext_vector_type(8))) short short8;
typedef __attribute__((ext_vector_type(4))) float f32x4;

__device__ __forceinline__ unsigned short bf16_rne(float f) {
    unsigned int u = __float_as_uint(f);
    return (unsigned short)((u + 0x7FFFu + ((u >> 16) & 1u)) >> 16);
}

// HW packed f32->bf16 (2 elems / inst), gfx950
__device__ __forceinline__ unsigned int cvt_pk_bf16(float lo, float hi) {
    unsigned int r;
    asm("v_cvt_pk_bf16_f32 %0, %1, %2" : "=v"(r) : "v"(lo), "v"(hi));
    return r;
}

__device__ __forceinline__ float exp2_hw(float x) {
    float r;
    asm("v_exp_f32 %0, %1" : "=v"(r) : "v"(x));
    return r;
}

__device__ __forceinline__ unsigned char f32_to_fp8_sw(float f) {
    if (!(f == f)) return 0x7f;
    unsigned u = __float_as_uint(f);
    unsigned s = (u >> 24) & 0x80u;
    float a = fabsf(f);
    if (a >= 464.f) return (unsigned char)(s | 0x7e);
    int e = (int)((u >> 23) & 0xff) - 127;
    if (e < -6) {
        int q = (int)fminf(fmaxf(a * 512.0f + 0.5f, 0.f), 7.f);
        return (unsigned char)(s | q);
    }
    unsigned m = u & 0x7fffffu;
    unsigned keep = m >> 20, rest = m & 0xfffffu;
    keep += (rest > 0x80000u || (rest == 0x80000u && (keep & 1u))) ? 1u : 0u;
    if (keep == 8u) { keep = 0u; ++e; if (e > 8) return (unsigned char)(s | 0x7e); }
    return (unsigned char)(s | ((unsigned)(e + 7) << 3) | keep);
}

__device__ __forceinline__ unsigned int pk4_fp8(float a, float b, float c, float d) {
#if __has_builtin(__builtin_amdgcn_cvt_pk_fp8_f32)
    int r = __builtin_amdgcn_cvt_pk_fp8_f32(a, b, 0, false);
    r     = __builtin_amdgcn_cvt_pk_fp8_f32(c, d, r, true);
    return (unsigned int)r;
#else
    return (unsigned)f32_to_fp8_sw(a) | ((unsigned)f32_to_fp8_sw(b) << 8) |
           ((unsigned)f32_to_fp8_sw(c) << 16) | ((unsigned)f32_to_fp8_sw(d) << 24);
#endif
}

// gelu tanh-form: x * sigmoid(1.5957691*(x + 0.044715 x^3))
// exp2 arg folded: t = x*fma(-0.10294357, x^2, -2.3022077); sig = 1/(1+2^t)
// 4 elems with pair-batched rcp (2 trans saved / 4 elems)
__device__ __forceinline__ f32x4 gelu4(f32x4 a) {
    float d0, d1, d2, d3;
    {
        float t0 = a[0] * fmaf(-0.10294357f, a[0] * a[0], -2.3022077f);
        float t1 = a[1] * fmaf(-0.10294357f, a[1] * a[1], -2.3022077f);
        float t2 = a[2] * fmaf(-0.10294357f, a[2] * a[2], -2.3022077f);
        float t3 = a[3] * fmaf(-0.10294357f, a[3] * a[3], -2.3022077f);
        d0 = 1.0f + exp2_hw(t0);
        d1 = 1.0f + exp2_hw(t1);
        d2 = 1.0f + exp2_hw(t2);
        d3 = 1.0f + exp2_hw(t3);
    }
    float r01 = __builtin_amdgcn_rcpf(d0 * d1);
    float r23 = __builtin_amdgcn_rcpf(d2 * d3);
    f32x4 g;
    g[0] = a[0] * d1 * r01;
    g[1] = a[1] * d0 * r01;
    g[2] = a[2] * d3 * r23;
    g[3] = a[3] * d2 * r23;
    return g;
}

// W1p bf16 A-frags: t = ((mt*5+kk)*64 + lane)*8 + j ; A[m=mt*16+nl][k=kk*32+q*8+j] = W1[k][m]
__global__ __launch_bounds__(256) void pack_w1(const float* __restrict__ W1,
                                               unsigned short* __restrict__ W1p) {
    int t = blockIdx.x * 256 + threadIdx.x;
    if (t >= W1P_ELEMS) return;
    int j = t & 7, ln = (t >> 3) & 63, g = t >> 9;
    int kk = g % 5, mt = g / 5;
    int nl = ln & 15, q = ln >> 4;
    int k = kk * 32 + q * 8 + j, m = mt * 16 + nl;
    W1p[t] = bf16_rne(W1[(size_t)k * HH + m]);
}
// W2p fp8 A-frags: t = ((jt*16+kk)*64 + lane)*8 + j ; A[m=jt*16+nl][k=kk*32+q*8+j] = W2[k][m]
__global__ __launch_bounds__(256) void pack_w2_fp8(const float* __restrict__ W2,
                                                   unsigned char* __restrict__ W2p) {
    int t = blockIdx.x * 256 + threadIdx.x;
    if (t >= W2P_BYTES) return;
    int j = t & 7, ln = (t >> 3) & 63, g = t >> 9;
    int kk = g & 15, jt = g >> 4;
    int nl = ln & 15, q = ln >> 4;
    int k = kk * 32 + q * 8 + j, m = jt * 16 + nl;
    float v = W2[(size_t)k * DDYN + m];
#if __has_builtin(__builtin_amdgcn_cvt_pk_fp8_f32)
    W2p[t] = (unsigned char)(__builtin_amdgcn_cvt_pk_fp8_f32(v, v, 0, false) & 0xff);
#else
    W2p[t] = f32_to_fp8_sw(v);
#endif
}

// h: [node(64)][hid(512)] fp8, XOR-swizzled 8B slots: byte = node*512 + ((sub8 ^ (node&15))<<3) + o4
// xself: [64][40] f32, 16B chunks 0..7 stored at chunk ^ (node&7); chunks 8,9 linear.
// Register discipline: cap = 64 (unified VGPR+AGPR at 8 waves/EU). NOTHING is held live
// across a barrier except the MFMA accumulators. Spills = global traffic (r1-r4 lesson).
__global__ __launch_bounds__(NTHR, 8) void step_mfma(
    const float* __restrict__ xsrc, float* __restrict__ xdst,
    const int* __restrict__ index,
    const unsigned short* __restrict__ W1p, const float* __restrict__ b1,
    const unsigned char* __restrict__ W2p, const float* __restrict__ b2)
{
    __shared__ alignas(16) unsigned char smem[LDS_TOT];
    unsigned short* z = (unsigned short*)smem;          // [64][ZS] bf16, dies after barrier 2
    unsigned char*  h = smem + H_OFF;                   // [64][512] fp8 swizzled
    float* xself = (float*)(smem + XS_OFF);             // [64][40] f32 self rows (chunk-swizzled)
    float* stg   = (float*)smem;                        // GEMM2 kh=1 partials (overlay z)

    const int tid = threadIdx.x;
    const int w   = tid >> 6;        // 0..15
    const int ln  = tid & 63;
    const int nl  = ln & 15;
    const int q   = ln >> 4;
    const int n0  = blockIdx.x * TM;
    const int b   = blockIdx.y;
    const size_t xbase = (size_t)b * NN * DDIM;

    // GEMM2 wave roles
    const int nt2 = w & 3;           // node tile
    const int jt  = (w >> 2) & 1;    // output j tile
    const int kh  = w >> 3;          // K half

    // ---- Phase 1: gather -> z bf16 (64 nodes x 4 nbrs x 10 float4 = 2560 tasks);
    //      k==0 (self row) also stashed f32 (chunk-swizzled) in xself for the epilogue ----
    if (n0 + TM <= NN) {   // fast path (640 of 641 blocks): 3 independent load chains up front
        const int e0 = tid, e1 = tid + NTHR, e2 = tid + 2 * NTHR;
        const bool has2 = (e2 < TM * 40);
        int m0 = e0 / 40, r0 = e0 - m0 * 40, k0 = r0 / 10, q0 = r0 - k0 * 10;
        int m1 = e1 / 40, r1 = e1 - m1 * 40, k1 = r1 / 10, q1 = r1 - k1 * 10;
        int m2 = e2 / 40, r2 = e2 - m2 * 40, k2 = r2 / 10, q2 = r2 - k2 * 10;
        int nb0 = index[(n0 + m0) * 4 + k0];
        int nb1 = index[(n0 + m1) * 4 + k1];
        int nb2 = has2 ? index[(n0 + m2) * 4 + k2] : nb1;
        float4 v0 = ((const float4*)(xsrc + xbase + (size_t)nb0 * DDIM))[q0];
        float4 v1 = ((const float4*)(xsrc + xbase + (size_t)nb1 * DDIM))[q1];
        float4 v2 = ((const float4*)(xsrc + xbase + (size_t)nb2 * DDIM))[has2 ? q2 : q1];
        *(uint2*)(z + m0 * ZS + k0 * 40 + q0 * 4) =
            make_uint2(cvt_pk_bf16(v0.x, v0.y), cvt_pk_bf16(v0.z, v0.w));
        if (k0 == 0) { int c = (q0 < 8) ? (q0 ^ (m0 & 7)) : q0;
                       *(float4*)(xself + m0 * 40 + c * 4) = v0; }
        *(uint2*)(z + m1 * ZS + k1 * 40 + q1 * 4) =
            make_uint2(cvt_pk_bf16(v1.x, v1.y), cvt_pk_bf16(v1.z, v1.w));
        if (k1 == 0) { int c = (q1 < 8) ? (q1 ^ (m1 & 7)) : q1;
                       *(float4*)(xself + m1 * 40 + c * 4) = v1; }
        if (has2) {
            *(uint2*)(z + m2 * ZS + k2 * 40 + q2 * 4) =
                make_uint2(cvt_pk_bf16(v2.x, v2.y), cvt_pk_bf16(v2.z, v2.w));
            if (k2 == 0) { int c = (q2 < 8) ? (q2 ^ (m2 & 7)) : q2;
                           *(float4*)(xself + m2 * 40 + c * 4) = v2; }
        }
    } else {
        for (int e = tid; e < TM * 4 * 10; e += NTHR) {
            int m = e / 40, r = e - m * 40;
            int k = r / 10, qq = r - k * 10;
            unsigned lo = 0, hi = 0;
            int n = n0 + m;
            float4 v = make_float4(0.f, 0.f, 0.f, 0.f);
            if (n < NN) {
                int nb = index[n * 4 + k];
                v = ((const float4*)(xsrc + xbase + (size_t)nb * DDIM))[qq];
                lo = cvt_pk_bf16(v.x, v.y);
                hi = cvt_pk_bf16(v.z, v.w);
            }
            *(uint2*)(z + m * ZS + k * 40 + qq * 4) = make_uint2(lo, hi);
            if (k == 0) {
                int c = (qq < 8) ? (qq ^ (m & 7)) : qq;
                *(float4*)(xself + m * 40 + c * 4) = v;
            }
        }
    }
    __syncthreads();   // barrier 1: z + xself ready

    // ---- Phase 2: GEMM1  h^T = W1^T(A) . z^T(B) ; wave owns hid tiles w*2, w*2+1; 4 node tiles.
    //      No explicit double-buffer (reg cap). ----
    const unsigned short* w1b = W1p + ((size_t)(w * 2) * 5) * 512 + ln * 8;
    f32x4 acc[2][4];
    #pragma unroll
    for (int i = 0; i < 2; ++i) {
        float4 bv = *(const float4*)(b1 + (w * 2 + i) * 16 + q * 4);
        f32x4 a; a[0] = bv.x; a[1] = bv.y; a[2] = bv.z; a[3] = bv.w;
        #pragma unroll
        for (int nt = 0; nt < 4; ++nt) acc[i][nt] = a;
    }
    #pragma unroll
    for (int kk = 0; kk < 5; ++kk) {
        short8 afr0 = *(const short8*)(w1b + kk * 512);
        short8 afr1 = *(const short8*)(w1b + (5 + kk) * 512);
        #pragma unroll
        for (int nt = 0; nt < 4; ++nt) {
            short8 bfr = *(const short8*)(z + (nt * 16 + nl) * ZS + kk * 32 + q * 8);
            acc[0][nt] = __builtin_amdgcn_mfma_f32_16x16x32_bf16(afr0, bfr, acc[0][nt], 0, 0, 0);
            acc[1][nt] = __builtin_amdgcn_mfma_f32_16x16x32_bf16(afr1, bfr, acc[1][nt], 0, 0, 0);
        }
    }
    // NO barrier here: P3 writes h (disjoint from z); nothing reads h until barrier 2.

    // ---- Phase 3: h = fp8(gelu(acc)) : one b32 write per (i,nt); acc dies here ----
    #pragma unroll
    for (int i = 0; i < 2; ++i) {
        const int hid  = (w * 2 + i) * 16 + q * 4;
        const int sub8 = hid >> 3;
        const int o4   = (q & 1) << 2;
        #pragma unroll
        for (int nt = 0; nt < 4; ++nt) {
            f32x4 g = gelu4(acc[i][nt]);
            unsigned int p = pk4_fp8(g[0], g[1], g[2], g[3]);
            int node = nt * 16 + nl;
            *(unsigned int*)(h + node * 512 + ((sub8 ^ (node & 15)) << 3) + o4) = p;
        }
    }
    __syncthreads();   // barrier 2: all h written; z dead from here. No regs live but ids.

    // ---- Phase 4: GEMM2 16-wave (kh x jt x nt), 8 MFMA/wave.
    //      W2p frags + b2 loaded HERE (L2-hot, shared by all blocks) so nothing
    //      crosses barrier 2 in registers -> no spill under the 64-reg cap. ----
    const int hrow = nt2 * 16 + nl;
    long long wf[8];
    #pragma unroll
    for (int kk = 0; kk < 8; ++kk)
        __builtin_memcpy(&wf[kk], W2p + (size_t)(((jt * 16 + kh * 8 + kk) * 64 + ln) * 8), 8);
    f32x4 acc2;
    if (kh == 0) {
        float4 bv = *(const float4*)(b2 + jt * 16 + q * 4);
        acc2[0] = bv.x; acc2[1] = bv.y; acc2[2] = bv.z; acc2[3] = bv.w;
    } else {
        acc2[0] = acc2[1] = acc2[2] = acc2[3] = 0.f;
    }
    #pragma unroll
    for (int kk = 0; kk < 8; ++kk) {
        int kg = kh * 8 + kk;
        long long bfr;
        __builtin_memcpy(&bfr, h + hrow * 512 + (((kg * 4 + q) ^ (hrow & 15)) << 3), 8);
        acc2 = __builtin_amdgcn_mfma_f32_16x16x32_fp8_fp8(wf[kk], bfr, acc2, 0, 0, 0);
    }
    if (kh == 1)   // stage partial in stg (overlay z; z dead since barrier 2)
        *(f32x4*)(stg + ((w - 8) * 64 + ln) * 4) = acc2;
    __syncthreads();   // barrier 3: partials staged

    // ---- Phase 4b (kh==0 waves): combine partials, fmaf update into xself (in LDS) ----
    if (kh == 0) {
        f32x4 p = *(const f32x4*)(stg + (w * 64 + ln) * 4);
        int c = (jt * 4 + q) ^ (hrow & 7);
        float* xp = xself + hrow * 40 + c * 4;
        float4 s = *(const float4*)xp;
        s.x = fmaf(STEPSZ, acc2[0] + p[0], s.x);
        s.y = fmaf(STEPSZ, acc2[1] + p[1], s.y);
        s.z = fmaf(STEPSZ, acc2[2] + p[2], s.z);
        s.w = fmaf(STEPSZ, acc2[3] + p[3], s.w);
        *(float4*)xp = s;
    }
    __syncthreads();   // barrier 4: xself updated

    // ---- Phase 5: coalesced full-row epilogue, 640 float4 tasks ----
    if (tid < TM * 10) {
        int m = tid / 10, p = tid - m * 10;
        int n = n0 + m;
        if (n < NN) {
            int c = (p < 8) ? (p ^ (m & 7)) : p;
            float4 v = *(const float4*)(xself + m * 40 + c * 4);
            *(float4*)(xdst + xbase + (size_t)n * DDIM + p * 4) = v;
        }
    }
}

// ================= fallback f32 path (used only if ws too small) =================
constexpr int FTM = 16;
__device__ __forceinline__ float gelu_f(float x) {
    float t = x * fmaf(-0.10294357f, x * x, -2.3022077f);
    return x * __builtin_amdgcn_rcpf(1.0f + exp2_hw(t));
}
__global__ __launch_bounds__(256) void step_f32(
    const float* __restrict__ xsrc, float* __restrict__ xdst,
    const int* __restrict__ index,
    const float* __restrict__ W1, const float* __restrict__ b1,
    const float* __restrict__ W2, const float* __restrict__ b2)
{
    __shared__ float z_lds[FTM][160];
    __shared__ float h_lds[FTM][HH];
    __shared__ float fz_lds[FTM][DDYN];
    const int tid = threadIdx.x, tile = blockIdx.x, b = blockIdx.y;
    const int n0 = tile * FTM;
    const int nvalid = min(FTM, NN - n0);
    for (int e = tid; e < FTM * 4 * 10; e += 256) {
        int m = e / 40, r = e % 40, k = r / 10, qq = r % 10;
        float4 v = make_float4(0.f, 0.f, 0.f, 0.f);
        int n = n0 + m;
        if (n < NN) {
            int nb = index[n * 4 + k];
            v = ((const float4*)(xsrc + ((size_t)b * NN + nb) * DDIM))[qq];
        }
        ((float4*)&z_lds[m][k * DDIM])[qq] = v;
    }
    __syncthreads();
    const int c0 = 2 * tid;
    float2 acc[FTM];
    {
        float bx = b1[c0], by = b1[c0 + 1];
        #pragma unroll
        for (int m = 0; m < FTM; ++m) { acc[m].x = bx; acc[m].y = by; }
    }
    for (int kd = 0; kd < 160; kd += 4) {
        float2 w0 = *(const float2*)(W1 + (size_t)(kd + 0) * HH + c0);
        float2 w1 = *(const float2*)(W1 + (size_t)(kd + 1) * HH + c0);
        float2 w2 = *(const float2*)(W1 + (size_t)(kd + 2) * HH + c0);
        float2 w3 = *(const float2*)(W1 + (size_t)(kd + 3) * HH + c0);
        #pragma unroll
        for (int m = 0; m < FTM; ++m) {
            float4 zv = *(const float4*)&z_lds[m][kd];
            acc[m].x = fmaf(zv.x, w0.x, acc[m].x); acc[m].y = fmaf(zv.x, w0.y, acc[m].y);
            acc[m].x = fmaf(zv.y, w1.x, acc[m].x); acc[m].y = fmaf(zv.y, w1.y, acc[m].y);
            acc[m].x = fmaf(zv.z, w2.x, acc[m].x); acc[m].y = fmaf(zv.z, w2.y, acc[m].y);
            acc[m].x = fmaf(zv.w, w3.x, acc[m].x); acc[m].y = fmaf(zv.w, w3.y, acc[m].y);
        }
    }
    #pragma unroll
    for (int m = 0; m < FTM; ++m) {
        h_lds[m][c0]     = gelu_f(acc[m].x);
        h_lds[m][c0 + 1] = gelu_f(acc[m].y);
    }
    __syncthreads();
    {
        const int j = tid & 31, mg = tid >> 5;
        float a0 = b2[j], a1 = a0;
        for (int c = 0; c < HH; c += 4) {
            float wa = W2[(size_t)(c + 0) * DDYN + j];
            float wb = W2[(size_t)(c + 1) * DDYN + j];
            float wc = W2[(size_t)(c + 2) * DDYN + j];
            float wd = W2[(size_t)(c + 3) * DDYN + j];
            float4 h0 = *(const float4*)&h_lds[mg][c];
            float4 h1 = *(const float4*)&h_lds[mg + 8][c];
            a0 = fmaf(h0.x, wa, a0); a0 = fmaf(h0.y, wb, a0);
            a0 = fmaf(h0.z, wc, a0); a0 = fmaf(h0.w, wd, a0);
            a1 = fmaf(h1.x, wa, a1); a1 = fmaf(h1.y, wb, a1);
            a1 = fmaf(h1.z, wc, a1); a1 = fmaf(h1.w, wd, a1);
        }
        fz_lds[mg][j] = a0; fz_lds[mg + 8][j] = a1;
    }
    __syncthreads();
    const size_t base = ((size_t)b * NN + n0) * (size_t)DDIM;
    for (int e = tid; e < nvalid * DDIM; e += 256) {
        int m = e / DDIM, d = e % DDIM;
        float v = xsrc[base + e];
        if (d < DDYN) v = fmaf(STEPSZ, fz_lds[m][d], v);
        xdst[base + e] = v;
    }
}

extern "C" void kernel_launch(void* const* d_in, const int* in_sizes, int n_in,
                              void* d_out, int out_size, void* d_ws, size_t ws_size,
                              hipStream_t stream) {
    const float* x   = (const float*)d_in[0];
    const int*   idx = (const int*)  d_in[1];
    const float* W1  = (const float*)d_in[2];
    const float* b1  = (const float*)d_in[3];
    const float* W2  = (const float*)d_in[4];
    const float* b2  = (const float*)d_in[5];
    float* out  = (float*)d_out;
    float* xbuf = (float*)d_ws;

    const size_t need = X_BYTES + (size_t)W1P_ELEMS * 2 + W2P_BYTES;
    if (ws_size >= need) {
        unsigned short* W1p = (unsigned short*)((char*)d_ws + X_BYTES);
        unsigned char*  W2p = (unsigned char*)(W1p + W1P_ELEMS);
        pack_w1<<<(W1P_ELEMS + 255) / 256, 256, 0, stream>>>(W1, W1p);
        pack_w2_fp8<<<(W2P_BYTES + 255) / 256, 256, 0, stream>>>(W2, W2p);
        dim3 grid((NN + TM - 1) / TM, BB), block(NTHR);
        step_mfma<<<grid, block, 0, stream>>>(x,    xbuf, idx, W1p, b1, W2p, b2);
        step_mfma<<<grid, block, 0, stream>>>(xbuf, out,  idx, W1p, b1, W2p, b2);
        step_mfma<<<grid, block, 0, stream>>>(out,  xbuf, idx, W1p, b1, W2p, b2);
        step_mfma<<<grid, block, 0, stream>>>(xbuf, out,  idx, W1p, b1, W2p, b2);
    } else {
        dim3 grid((NN + FTM - 1) / FTM, BB), block(256);
        step_f32<<<grid, block, 0, stream>>>(x,    xbuf, idx, W1, b1, W2, b2);
        step_f32<<<grid, block, 0, stream>>>(xbuf, out,  idx, W1, b1, W2, b2);
        step_f32<<<grid, block, 0, stream>>>(out,  xbuf, idx, W1, b1, W2, b2);
        step_f32<<<grid, block, 0, stream>>>(xbuf, out,  idx, W1, b1, W2, b2);
    }
}

// Round 6
// 559.020 us; speedup vs baseline: 1.1051x; 1.1051x over previous
//
#include <hip/hip_runtime.h>
#include <math.h>

// B=8, N=40962, D=40, H=512, D_DYN=32, 4 steps, dt=0.1
constexpr int BB   = 8;
constexpr int NN   = 40962;
constexpr int DDIM = 40;
constexpr int HH   = 512;
constexpr int DDYN = 32;
constexpr float STEPSZ = 0.1f;

constexpr int TM   = 64;      // nodes per block
constexpr int NTHR = 1024;    // 16 waves
constexpr int ZS   = 168;     // z row stride (bf16): 336B -> conflict-free b128 reads

constexpr size_t X_ELEMS = (size_t)BB * NN * DDIM;
constexpr size_t X_BYTES = X_ELEMS * 4;
constexpr int W1P_ELEMS = 32 * 5 * 64 * 8;   // bf16 A-frags [mt][kk][lane][j]
constexpr int W2P_BYTES = 2 * 16 * 64 * 8;   // fp8 A-frags  [jt][kk][lane][j]

// LDS: z [64][168] bf16 = 21504 | h [64][512] fp8 = 32768 | xself [64][40] f32 = 10240
// stg (8 waves x 64 lanes x 16B = 8192) overlays z (dead after barrier 2).
// Total 64512 <= 64KiB -> 2 blocks/CU.
constexpr int Z_BYTES = TM * ZS * 2;             // 21504
constexpr int H_OFF   = Z_BYTES;                 // 21504
constexpr int H_BYTES = TM * HH;                 // 32768
constexpr int XS_OFF  = H_OFF + H_BYTES;         // 54272
constexpr int LDS_TOT = XS_OFF + TM * DDIM * 4;  // 64512

typedef __attribute__((ext_vector_type(8))) short short8;
typedef __attribute__((ext_vector_type(4))) float f32x4;

__device__ __forceinline__ unsigned short bf16_rne(float f) {
    unsigned int u = __float_as_uint(f);
    return (unsigned short)((u + 0x7FFFu + ((u >> 16) & 1u)) >> 16);
}

// HW packed f32->bf16 (2 elems / inst), gfx950
__device__ __forceinline__ unsigned int cvt_pk_bf16(float lo, float hi) {
    unsigned int r;
    asm("v_cvt_pk_bf16_f32 %0, %1, %2" : "=v"(r) : "v"(lo), "v"(hi));
    return r;
}

__device__ __forceinline__ float exp2_hw(float x) {
    float r;
    asm("v_exp_f32 %0, %1" : "=v"(r) : "v"(x));
    return r;
}

__device__ __forceinline__ unsigned char f32_to_fp8_sw(float f) {
    if (!(f == f)) return 0x7f;
    unsigned u = __float_as_uint(f);
    unsigned s = (u >> 24) & 0x80u;
    float a = fabsf(f);
    if (a >= 464.f) return (unsigned char)(s | 0x7e);
    int e = (int)((u >> 23) & 0xff) - 127;
    if (e < -6) {
        int q = (int)fminf(fmaxf(a * 512.0f + 0.5f, 0.f), 7.f);
        return (unsigned char)(s | q);
    }
    unsigned m = u & 0x7fffffu;
    unsigned keep = m >> 20, rest = m & 0xfffffu;
    keep += (rest > 0x80000u || (rest == 0x80000u && (keep & 1u))) ? 1u : 0u;
    if (keep == 8u) { keep = 0u; ++e; if (e > 8) return (unsigned char)(s | 0x7e); }
    return (unsigned char)(s | ((unsigned)(e + 7) << 3) | keep);
}

__device__ __forceinline__ unsigned int pk4_fp8(float a, float b, float c, float d) {
#if __has_builtin(__builtin_amdgcn_cvt_pk_fp8_f32)
    int r = __builtin_amdgcn_cvt_pk_fp8_f32(a, b, 0, false);
    r     = __builtin_amdgcn_cvt_pk_fp8_f32(c, d, r, true);
    return (unsigned int)r;
#else
    return (unsigned)f32_to_fp8_sw(a) | ((unsigned)f32_to_fp8_sw(b) << 8) |
           ((unsigned)f32_to_fp8_sw(c) << 16) | ((unsigned)f32_to_fp8_sw(d) << 24);
#endif
}

// gelu tanh-form: x * sigmoid(1.5957691*(x + 0.044715 x^3))
// exp2 arg folded: t = x*fma(-0.10294357, x^2, -2.3022077); sig = 1/(1+2^t)
// 4 elems with pair-batched rcp (2 trans saved / 4 elems)
__device__ __forceinline__ f32x4 gelu4(f32x4 a) {
    float d0, d1, d2, d3;
    {
        float t0 = a[0] * fmaf(-0.10294357f, a[0] * a[0], -2.3022077f);
        float t1 = a[1] * fmaf(-0.10294357f, a[1] * a[1], -2.3022077f);
        float t2 = a[2] * fmaf(-0.10294357f, a[2] * a[2], -2.3022077f);
        float t3 = a[3] * fmaf(-0.10294357f, a[3] * a[3], -2.3022077f);
        d0 = 1.0f + exp2_hw(t0);
        d1 = 1.0f + exp2_hw(t1);
        d2 = 1.0f + exp2_hw(t2);
        d3 = 1.0f + exp2_hw(t3);
    }
    float r01 = __builtin_amdgcn_rcpf(d0 * d1);
    float r23 = __builtin_amdgcn_rcpf(d2 * d3);
    f32x4 g;
    g[0] = a[0] * d1 * r01;
    g[1] = a[1] * d0 * r01;
    g[2] = a[2] * d3 * r23;
    g[3] = a[3] * d2 * r23;
    return g;
}

// One GEMM1 half: acc[4] covers 4 node tiles for ONE hid tile (16 AGPRs live, not 32).
__device__ __forceinline__ void gemm1_half(const unsigned short* __restrict__ w1h,
                                           const unsigned short* z,
                                           f32x4 acc[4], int nl, int q) {
    #pragma unroll
    for (int kk = 0; kk < 5; ++kk) {
        short8 afr = *(const short8*)(w1h + kk * 512);
        #pragma unroll
        for (int nt = 0; nt < 4; ++nt) {
            short8 bfr = *(const short8*)(z + (nt * 16 + nl) * ZS + kk * 32 + q * 8);
            acc[nt] = __builtin_amdgcn_mfma_f32_16x16x32_bf16(afr, bfr, acc[nt], 0, 0, 0);
        }
    }
}

__device__ __forceinline__ void gelu_pack_store(unsigned char* h, f32x4 acc[4],
                                                int hid, int nl, int q) {
    const int sub8 = hid >> 3;
    const int o4   = (q & 1) << 2;
    #pragma unroll
    for (int nt = 0; nt < 4; ++nt) {
        f32x4 g = gelu4(acc[nt]);
        unsigned int p = pk4_fp8(g[0], g[1], g[2], g[3]);
        int node = nt * 16 + nl;
        *(unsigned int*)(h + node * 512 + ((sub8 ^ (node & 15)) << 3) + o4) = p;
    }
}

// W1p bf16 A-frags: t = ((mt*5+kk)*64 + lane)*8 + j ; A[m=mt*16+nl][k=kk*32+q*8+j] = W1[k][m]
__global__ __launch_bounds__(256) void pack_w1(const float* __restrict__ W1,
                                               unsigned short* __restrict__ W1p) {
    int t = blockIdx.x * 256 + threadIdx.x;
    if (t >= W1P_ELEMS) return;
    int j = t & 7, ln = (t >> 3) & 63, g = t >> 9;
    int kk = g % 5, mt = g / 5;
    int nl = ln & 15, q = ln >> 4;
    int k = kk * 32 + q * 8 + j, m = mt * 16 + nl;
    W1p[t] = bf16_rne(W1[(size_t)k * HH + m]);
}
// W2p fp8 A-frags: t = ((jt*16+kk)*64 + lane)*8 + j ; A[m=jt*16+nl][k=kk*32+q*8+j] = W2[k][m]
__global__ __launch_bounds__(256) void pack_w2_fp8(const float* __restrict__ W2,
                                                   unsigned char* __restrict__ W2p) {
    int t = blockIdx.x * 256 + threadIdx.x;
    if (t >= W2P_BYTES) return;
    int j = t & 7, ln = (t >> 3) & 63, g = t >> 9;
    int kk = g & 15, jt = g >> 4;
    int nl = ln & 15, q = ln >> 4;
    int k = kk * 32 + q * 8 + j, m = jt * 16 + nl;
    float v = W2[(size_t)k * DDYN + m];
#if __has_builtin(__builtin_amdgcn_cvt_pk_fp8_f32)
    W2p[t] = (unsigned char)(__builtin_amdgcn_cvt_pk_fp8_f32(v, v, 0, false) & 0xff);
#else
    W2p[t] = f32_to_fp8_sw(v);
#endif
}

// h: [node(64)][hid(512)] fp8, XOR-swizzled 8B slots: byte = node*512 + ((sub8 ^ (node&15))<<3) + o4
// xself: [64][40] f32, 16B chunks 0..7 stored at chunk ^ (node&7); chunks 8,9 linear.
// Register discipline: 64-reg cap at 8 waves/EU splits as VGPR+AGPR (unified file).
// acc[2][4]=32 AGPRs starved the VGPR side to 32 -> spills -> global traffic (r1-r5).
// Fix: sequential hid-tile halves, 16 AGPRs live max.
__global__ __launch_bounds__(NTHR, 8) void step_mfma(
    const float* __restrict__ xsrc, float* __restrict__ xdst,
    const int* __restrict__ index,
    const unsigned short* __restrict__ W1p, const float* __restrict__ b1,
    const unsigned char* __restrict__ W2p, const float* __restrict__ b2)
{
    __shared__ alignas(16) unsigned char smem[LDS_TOT];
    unsigned short* z = (unsigned short*)smem;          // [64][ZS] bf16, dies after barrier 2
    unsigned char*  h = smem + H_OFF;                   // [64][512] fp8 swizzled
    float* xself = (float*)(smem + XS_OFF);             // [64][40] f32 self rows (chunk-swizzled)
    float* stg   = (float*)smem;                        // GEMM2 kh=1 partials (overlay z)

    const int tid = threadIdx.x;
    const int w   = tid >> 6;        // 0..15
    const int ln  = tid & 63;
    const int nl  = ln & 15;
    const int q   = ln >> 4;
    const int n0  = blockIdx.x * TM;
    const int b   = blockIdx.y;
    const size_t xbase = (size_t)b * NN * DDIM;

    // GEMM2 wave roles
    const int nt2 = w & 3;           // node tile
    const int jt  = (w >> 2) & 1;    // output j tile
    const int kh  = w >> 3;          // K half

    // ---- Phase 1: gather -> z bf16 (64 nodes x 4 nbrs x 10 float4 = 2560 tasks);
    //      k==0 (self row) also stashed f32 (chunk-swizzled) in xself for the epilogue ----
    if (n0 + TM <= NN) {   // fast path (640 of 641 blocks): 3 independent load chains up front
        const int e0 = tid, e1 = tid + NTHR, e2 = tid + 2 * NTHR;
        const bool has2 = (e2 < TM * 40);
        int m0 = e0 / 40, r0 = e0 - m0 * 40, k0 = r0 / 10, q0 = r0 - k0 * 10;
        int m1 = e1 / 40, r1 = e1 - m1 * 40, k1 = r1 / 10, q1 = r1 - k1 * 10;
        int m2 = e2 / 40, r2 = e2 - m2 * 40, k2 = r2 / 10, q2 = r2 - k2 * 10;
        int nb0 = index[(n0 + m0) * 4 + k0];
        int nb1 = index[(n0 + m1) * 4 + k1];
        int nb2 = has2 ? index[(n0 + m2) * 4 + k2] : nb1;
        float4 v0 = ((const float4*)(xsrc + xbase + (size_t)nb0 * DDIM))[q0];
        float4 v1 = ((const float4*)(xsrc + xbase + (size_t)nb1 * DDIM))[q1];
        float4 v2 = ((const float4*)(xsrc + xbase + (size_t)nb2 * DDIM))[has2 ? q2 : q1];
        *(uint2*)(z + m0 * ZS + k0 * 40 + q0 * 4) =
            make_uint2(cvt_pk_bf16(v0.x, v0.y), cvt_pk_bf16(v0.z, v0.w));
        if (k0 == 0) { int c = (q0 < 8) ? (q0 ^ (m0 & 7)) : q0;
                       *(float4*)(xself + m0 * 40 + c * 4) = v0; }
        *(uint2*)(z + m1 * ZS + k1 * 40 + q1 * 4) =
            make_uint2(cvt_pk_bf16(v1.x, v1.y), cvt_pk_bf16(v1.z, v1.w));
        if (k1 == 0) { int c = (q1 < 8) ? (q1 ^ (m1 & 7)) : q1;
                       *(float4*)(xself + m1 * 40 + c * 4) = v1; }
        if (has2) {
            *(uint2*)(z + m2 * ZS + k2 * 40 + q2 * 4) =
                make_uint2(cvt_pk_bf16(v2.x, v2.y), cvt_pk_bf16(v2.z, v2.w));
            if (k2 == 0) { int c = (q2 < 8) ? (q2 ^ (m2 & 7)) : q2;
                           *(float4*)(xself + m2 * 40 + c * 4) = v2; }
        }
    } else {
        for (int e = tid; e < TM * 4 * 10; e += NTHR) {
            int m = e / 40, r = e - m * 40;
            int k = r / 10, qq = r - k * 10;
            unsigned lo = 0, hi = 0;
            int n = n0 + m;
            float4 v = make_float4(0.f, 0.f, 0.f, 0.f);
            if (n < NN) {
                int nb = index[n * 4 + k];
                v = ((const float4*)(xsrc + xbase + (size_t)nb * DDIM))[qq];
                lo = cvt_pk_bf16(v.x, v.y);
                hi = cvt_pk_bf16(v.z, v.w);
            }
            *(uint2*)(z + m * ZS + k * 40 + qq * 4) = make_uint2(lo, hi);
            if (k == 0) {
                int c = (qq < 8) ? (qq ^ (m & 7)) : qq;
                *(float4*)(xself + m * 40 + c * 4) = v;
            }
        }
    }
    __syncthreads();   // barrier 1: z + xself ready

    // ---- Phase 2+3, half A (hid tile w*2): GEMM1 -> gelu -> h. acc dies before half B. ----
    const unsigned short* w1b = W1p + ((size_t)(w * 2) * 5) * 512 + ln * 8;
    {
        f32x4 acc[4];
        float4 bv = *(const float4*)(b1 + (w * 2) * 16 + q * 4);
        f32x4 a0; a0[0] = bv.x; a0[1] = bv.y; a0[2] = bv.z; a0[3] = bv.w;
        #pragma unroll
        for (int nt = 0; nt < 4; ++nt) acc[nt] = a0;
        gemm1_half(w1b, z, acc, nl, q);
        gelu_pack_store(h, acc, (w * 2) * 16 + q * 4, nl, q);
    }

    // ---- Phase 2+3, half B (hid tile w*2+1) ----
    f32x4 acc[4];
    {
        float4 bv = *(const float4*)(b1 + (w * 2 + 1) * 16 + q * 4);
        f32x4 a0; a0[0] = bv.x; a0[1] = bv.y; a0[2] = bv.z; a0[3] = bv.w;
        #pragma unroll
        for (int nt = 0; nt < 4; ++nt) acc[nt] = a0;
        gemm1_half(w1b + 5 * 512, z, acc, nl, q);
    }

    // prefetch this wave's 8 W2p fragments + b2 (L2 latency hidden under half-B gelu;
    // held across barrier 2 -- affordable now that only 16 AGPRs were ever live)
    long long wf[8];
    #pragma unroll
    for (int kk = 0; kk < 8; ++kk)
        __builtin_memcpy(&wf[kk], W2p + (size_t)(((jt * 16 + kh * 8 + kk) * 64 + ln) * 8), 8);
    float4 bv2 = make_float4(0.f, 0.f, 0.f, 0.f);
    if (kh == 0) bv2 = *(const float4*)(b2 + jt * 16 + q * 4);

    gelu_pack_store(h, acc, (w * 2 + 1) * 16 + q * 4, nl, q);
    __syncthreads();   // barrier 2: all h written; z dead from here

    // ---- Phase 4: GEMM2 16-wave (kh x jt x nt), 8 MFMA/wave, prefetched A-frags ----
    const int hrow = nt2 * 16 + nl;
    f32x4 acc2;
    acc2[0] = bv2.x; acc2[1] = bv2.y; acc2[2] = bv2.z; acc2[3] = bv2.w;
    #pragma unroll
    for (int kk = 0; kk < 8; ++kk) {
        int kg = kh * 8 + kk;
        long long bfr;
        __builtin_memcpy(&bfr, h + hrow * 512 + (((kg * 4 + q) ^ (hrow & 15)) << 3), 8);
        acc2 = __builtin_amdgcn_mfma_f32_16x16x32_fp8_fp8(wf[kk], bfr, acc2, 0, 0, 0);
    }
    if (kh == 1)   // stage partial in stg (overlay z; z dead since barrier 2)
        *(f32x4*)(stg + ((w - 8) * 64 + ln) * 4) = acc2;
    __syncthreads();   // barrier 3: partials staged

    // ---- Phase 4b (kh==0 waves): combine partials, fmaf update into xself (in LDS) ----
    if (kh == 0) {
        f32x4 p = *(const f32x4*)(stg + (w * 64 + ln) * 4);
        int c = (jt * 4 + q) ^ (hrow & 7);
        float* xp = xself + hrow * 40 + c * 4;
        float4 s = *(const float4*)xp;
        s.x = fmaf(STEPSZ, acc2[0] + p[0], s.x);
        s.y = fmaf(STEPSZ, acc2[1] + p[1], s.y);
        s.z = fmaf(STEPSZ, acc2[2] + p[2], s.z);
        s.w = fmaf(STEPSZ, acc2[3] + p[3], s.w);
        *(float4*)xp = s;
    }
    __syncthreads();   // barrier 4: xself updated

    // ---- Phase 5: coalesced full-row epilogue, 640 float4 tasks ----
    if (tid < TM * 10) {
        int m = tid / 10, p = tid - m * 10;
        int n = n0 + m;
        if (n < NN) {
            int c = (p < 8) ? (p ^ (m & 7)) : p;
            float4 v = *(const float4*)(xself + m * 40 + c * 4);
            *(float4*)(xdst + xbase + (size_t)n * DDIM + p * 4) = v;
        }
    }
}

// ================= fallback f32 path (used only if ws too small) =================
constexpr int FTM = 16;
__device__ __forceinline__ float gelu_f(float x) {
    float t = x * fmaf(-0.10294357f, x * x, -2.3022077f);
    return x * __builtin_amdgcn_rcpf(1.0f + exp2_hw(t));
}
__global__ __launch_bounds__(256) void step_f32(
    const float* __restrict__ xsrc, float* __restrict__ xdst,
    const int* __restrict__ index,
    const float* __restrict__ W1, const float* __restrict__ b1,
    const float* __restrict__ W2, const float* __restrict__ b2)
{
    __shared__ float z_lds[FTM][160];
    __shared__ float h_lds[FTM][HH];
    __shared__ float fz_lds[FTM][DDYN];
    const int tid = threadIdx.x, tile = blockIdx.x, b = blockIdx.y;
    const int n0 = tile * FTM;
    const int nvalid = min(FTM, NN - n0);
    for (int e = tid; e < FTM * 4 * 10; e += 256) {
        int m = e / 40, r = e % 40, k = r / 10, qq = r % 10;
        float4 v = make_float4(0.f, 0.f, 0.f, 0.f);
        int n = n0 + m;
        if (n < NN) {
            int nb = index[n * 4 + k];
            v = ((const float4*)(xsrc + ((size_t)b * NN + nb) * DDIM))[qq];
        }
        ((float4*)&z_lds[m][k * DDIM])[qq] = v;
    }
    __syncthreads();
    const int c0 = 2 * tid;
    float2 acc[FTM];
    {
        float bx = b1[c0], by = b1[c0 + 1];
        #pragma unroll
        for (int m = 0; m < FTM; ++m) { acc[m].x = bx; acc[m].y = by; }
    }
    for (int kd = 0; kd < 160; kd += 4) {
        float2 w0 = *(const float2*)(W1 + (size_t)(kd + 0) * HH + c0);
        float2 w1 = *(const float2*)(W1 + (size_t)(kd + 1) * HH + c0);
        float2 w2 = *(const float2*)(W1 + (size_t)(kd + 2) * HH + c0);
        float2 w3 = *(const float2*)(W1 + (size_t)(kd + 3) * HH + c0);
        #pragma unroll
        for (int m = 0; m < FTM; ++m) {
            float4 zv = *(const float4*)&z_lds[m][kd];
            acc[m].x = fmaf(zv.x, w0.x, acc[m].x); acc[m].y = fmaf(zv.x, w0.y, acc[m].y);
            acc[m].x = fmaf(zv.y, w1.x, acc[m].x); acc[m].y = fmaf(zv.y, w1.y, acc[m].y);
            acc[m].x = fmaf(zv.z, w2.x, acc[m].x); acc[m].y = fmaf(zv.z, w2.y, acc[m].y);
            acc[m].x = fmaf(zv.w, w3.x, acc[m].x); acc[m].y = fmaf(zv.w, w3.y, acc[m].y);
        }
    }
    #pragma unroll
    for (int m = 0; m < FTM; ++m) {
        h_lds[m][c0]     = gelu_f(acc[m].x);
        h_lds[m][c0 + 1] = gelu_f(acc[m].y);
    }
    __syncthreads();
    {
        const int j = tid & 31, mg = tid >> 5;
        float a0 = b2[j], a1 = a0;
        for (int c = 0; c < HH; c += 4) {
            float wa = W2[(size_t)(c + 0) * DDYN + j];
            float wb = W2[(size_t)(c + 1) * DDYN + j];
            float wc = W2[(size_t)(c + 2) * DDYN + j];
            float wd = W2[(size_t)(c + 3) * DDYN + j];
            float4 h0 = *(const float4*)&h_lds[mg][c];
            float4 h1 = *(const float4*)&h_lds[mg + 8][c];
            a0 = fmaf(h0.x, wa, a0); a0 = fmaf(h0.y, wb, a0);
            a0 = fmaf(h0.z, wc, a0); a0 = fmaf(h0.w, wd, a0);
            a1 = fmaf(h1.x, wa, a1); a1 = fmaf(h1.y, wb, a1);
            a1 = fmaf(h1.z, wc, a1); a1 = fmaf(h1.w, wd, a1);
        }
        fz_lds[mg][j] = a0; fz_lds[mg + 8][j] = a1;
    }
    __syncthreads();
    const size_t base = ((size_t)b * NN + n0) * (size_t)DDIM;
    for (int e = tid; e < nvalid * DDIM; e += 256) {
        int m = e / DDIM, d = e % DDIM;
        float v = xsrc[base + e];
        if (d < DDYN) v = fmaf(STEPSZ, fz_lds[m][d], v);
        xdst[base + e] = v;
    }
}

extern "C" void kernel_launch(void* const* d_in, const int* in_sizes, int n_in,
                              void* d_out, int out_size, void* d_ws, size_t ws_size,
                              hipStream_t stream) {
    const float* x   = (const float*)d_in[0];
    const int*   idx = (const int*)  d_in[1];
    const float* W1  = (const float*)d_in[2];
    const float* b1  = (const float*)d_in[3];
    const float* W2  = (const float*)d_in[4];
    const float* b2  = (const float*)d_in[5];
    float* out  = (float*)d_out;
    float* xbuf = (float*)d_ws;

    const size_t need = X_BYTES + (size_t)W1P_ELEMS * 2 + W2P_BYTES;
    if (ws_size >= need) {
        unsigned short* W1p = (unsigned short*)((char*)d_ws + X_BYTES);
        unsigned char*  W2p = (unsigned char*)(W1p + W1P_ELEMS);
        pack_w1<<<(W1P_ELEMS + 255) / 256, 256, 0, stream>>>(W1, W1p);
        pack_w2_fp8<<<(W2P_BYTES + 255) / 256, 256, 0, stream>>>(W2, W2p);
        dim3 grid((NN + TM - 1) / TM, BB), block(NTHR);
        step_mfma<<<grid, block, 0, stream>>>(x,    xbuf, idx, W1p, b1, W2p, b2);
        step_mfma<<<grid, block, 0, stream>>>(xbuf, out,  idx, W1p, b1, W2p, b2);
        step_mfma<<<grid, block, 0, stream>>>(out,  xbuf, idx, W1p, b1, W2p, b2);
        step_mfma<<<grid, block, 0, stream>>>(xbuf, out,  idx, W1p, b1, W2p, b2);
    } else {
        dim3 grid((NN + FTM - 1) / FTM, BB), block(256);
        step_f32<<<grid, block, 0, stream>>>(x,    xbuf, idx, W1, b1, W2, b2);
        step_f32<<<grid, block, 0, stream>>>(xbuf, out,  idx, W1, b1, W2, b2);
        step_f32<<<grid, block, 0, stream>>>(out,  xbuf, idx, W1, b1, W2, b2);
        step_f32<<<grid, block, 0, stream>>>(xbuf, out,  idx, W1, b1, W2, b2);
    }
}

// Round 8
// 536.259 us; speedup vs baseline: 1.1520x; 1.0424x over previous
//
#include <hip/hip_runtime.h>
#include <math.h>

// B=8, N=40962, D=40, H=512, D_DYN=32, 4 steps, dt=0.1
constexpr int BB   = 8;
constexpr int NN   = 40962;
constexpr int DDIM = 40;
constexpr int HH   = 512;
constexpr int DDYN = 32;
constexpr float STEPSZ = 0.1f;

constexpr int TM   = 64;      // nodes per block
constexpr int NTHR = 1024;    // 16 waves
constexpr int ZS   = 168;     // z row stride (bf16): 336B -> conflict-free b128 reads

constexpr size_t X_ELEMS = (size_t)BB * NN * DDIM;
constexpr size_t X_BYTES = X_ELEMS * 4;
constexpr int W1P_ELEMS = 32 * 5 * 64 * 8;   // bf16 A-frags [mt][kk][lane][j]
constexpr int W2P_BYTES = 2 * 16 * 64 * 8;   // fp8 A-frags  [jt][kk][lane][j]

// LDS: z [64][168] bf16 = 21504 | h [64][512] fp8 = 32768 | xself [64][40] f32 = 10240
// stg (8 waves x 64 lanes x 16B = 8192) overlays z (dead after barrier 2).
// Total 64512 <= 64KiB -> 2 blocks/CU (32 waves = HW cap).
constexpr int Z_BYTES = TM * ZS * 2;             // 21504
constexpr int H_OFF   = Z_BYTES;                 // 21504
constexpr int H_BYTES = TM * HH;                 // 32768
constexpr int XS_OFF  = H_OFF + H_BYTES;         // 54272
constexpr int LDS_TOT = XS_OFF + TM * DDIM * 4;  // 64512

typedef __attribute__((ext_vector_type(8))) short short8;
typedef __attribute__((ext_vector_type(4))) float f32x4;

__device__ __forceinline__ unsigned short bf16_rne(float f) {
    unsigned int u = __float_as_uint(f);
    return (unsigned short)((u + 0x7FFFu + ((u >> 16) & 1u)) >> 16);
}

// HW packed f32->bf16 (2 elems / inst), gfx950
__device__ __forceinline__ unsigned int cvt_pk_bf16(float lo, float hi) {
    unsigned int r;
    asm("v_cvt_pk_bf16_f32 %0, %1, %2" : "=v"(r) : "v"(lo), "v"(hi));
    return r;
}

__device__ __forceinline__ float exp2_hw(float x) {
    float r;
    asm("v_exp_f32 %0, %1" : "=v"(r) : "v"(x));
    return r;
}

__device__ __forceinline__ unsigned char f32_to_fp8_sw(float f) {
    if (!(f == f)) return 0x7f;
    unsigned u = __float_as_uint(f);
    unsigned s = (u >> 24) & 0x80u;
    float a = fabsf(f);
    if (a >= 464.f) return (unsigned char)(s | 0x7e);
    int e = (int)((u >> 23) & 0xff) - 127;
    if (e < -6) {
        int q = (int)fminf(fmaxf(a * 512.0f + 0.5f, 0.f), 7.f);
        return (unsigned char)(s | q);
    }
    unsigned m = u & 0x7fffffu;
    unsigned keep = m >> 20, rest = m & 0xfffffu;
    keep += (rest > 0x80000u || (rest == 0x80000u && (keep & 1u))) ? 1u : 0u;
    if (keep == 8u) { keep = 0u; ++e; if (e > 8) return (unsigned char)(s | 0x7e); }
    return (unsigned char)(s | ((unsigned)(e + 7) << 3) | keep);
}

__device__ __forceinline__ unsigned int pk4_fp8(float a, float b, float c, float d) {
#if __has_builtin(__builtin_amdgcn_cvt_pk_fp8_f32)
    int r = __builtin_amdgcn_cvt_pk_fp8_f32(a, b, 0, false);
    r     = __builtin_amdgcn_cvt_pk_fp8_f32(c, d, r, true);
    return (unsigned int)r;
#else
    return (unsigned)f32_to_fp8_sw(a) | ((unsigned)f32_to_fp8_sw(b) << 8) |
           ((unsigned)f32_to_fp8_sw(c) << 16) | ((unsigned)f32_to_fp8_sw(d) << 24);
#endif
}

// gelu tanh-form: x * sigmoid(1.5957691*(x + 0.044715 x^3))
// exp2 arg folded: t = x*fma(-0.10294357, x^2, -2.3022077); g = x / (1 + 2^t)
// Expressed as ext-vector C ops so the compiler may select v_pk_*_f32 (it owns the
// VGPR-pair alignment rules; hand-written VOP3P asm NaN'd in r7).
__device__ __forceinline__ f32x4 gelu4(f32x4 a) {
    f32x4 t = a * (a * a * -0.10294357f - 2.3022077f);
    f32x4 e;
    e[0] = exp2_hw(t[0]); e[1] = exp2_hw(t[1]);
    e[2] = exp2_hw(t[2]); e[3] = exp2_hw(t[3]);
    f32x4 d = e + 1.0f;
    f32x4 r;
    r[0] = __builtin_amdgcn_rcpf(d[0]); r[1] = __builtin_amdgcn_rcpf(d[1]);
    r[2] = __builtin_amdgcn_rcpf(d[2]); r[3] = __builtin_amdgcn_rcpf(d[3]);
    return a * r;
}

// One GEMM1 half: acc[4] covers 4 node tiles for ONE hid tile (16 AGPRs live, not 32).
__device__ __forceinline__ void gemm1_half(const unsigned short* __restrict__ w1h,
                                           const unsigned short* z,
                                           f32x4 acc[4], int nl, int q) {
    #pragma unroll
    for (int kk = 0; kk < 5; ++kk) {
        short8 afr = *(const short8*)(w1h + kk * 512);
        #pragma unroll
        for (int nt = 0; nt < 4; ++nt) {
            short8 bfr = *(const short8*)(z + (nt * 16 + nl) * ZS + kk * 32 + q * 8);
            acc[nt] = __builtin_amdgcn_mfma_f32_16x16x32_bf16(afr, bfr, acc[nt], 0, 0, 0);
        }
    }
}

__device__ __forceinline__ void gelu_pack_store(unsigned char* h, f32x4 acc[4],
                                                int hid, int nl, int q) {
    const int sub8 = hid >> 3;
    const int o4   = (q & 1) << 2;
    #pragma unroll
    for (int nt = 0; nt < 4; ++nt) {
        f32x4 g = gelu4(acc[nt]);
        unsigned int p = pk4_fp8(g[0], g[1], g[2], g[3]);
        int node = nt * 16 + nl;
        *(unsigned int*)(h + node * 512 + ((sub8 ^ (node & 15)) << 3) + o4) = p;
    }
}

// W1p bf16 A-frags: t = ((mt*5+kk)*64 + lane)*8 + j ; A[m=mt*16+nl][k=kk*32+q*8+j] = W1[k][m]
__global__ __launch_bounds__(256) void pack_w1(const float* __restrict__ W1,
                                               unsigned short* __restrict__ W1p) {
    int t = blockIdx.x * 256 + threadIdx.x;
    if (t >= W1P_ELEMS) return;
    int j = t & 7, ln = (t >> 3) & 63, g = t >> 9;
    int kk = g % 5, mt = g / 5;
    int nl = ln & 15, q = ln >> 4;
    int k = kk * 32 + q * 8 + j, m = mt * 16 + nl;
    W1p[t] = bf16_rne(W1[(size_t)k * HH + m]);
}
// W2p fp8 A-frags: t = ((jt*16+kk)*64 + lane)*8 + j ; A[m=jt*16+nl][k=kk*32+q*8+j] = W2[k][m]
__global__ __launch_bounds__(256) void pack_w2_fp8(const float* __restrict__ W2,
                                                   unsigned char* __restrict__ W2p) {
    int t = blockIdx.x * 256 + threadIdx.x;
    if (t >= W2P_BYTES) return;
    int j = t & 7, ln = (t >> 3) & 63, g = t >> 9;
    int kk = g & 15, jt = g >> 4;
    int nl = ln & 15, q = ln >> 4;
    int k = kk * 32 + q * 8 + j, m = jt * 16 + nl;
    float v = W2[(size_t)k * DDYN + m];
#if __has_builtin(__builtin_amdgcn_cvt_pk_fp8_f32)
    W2p[t] = (unsigned char)(__builtin_amdgcn_cvt_pk_fp8_f32(v, v, 0, false) & 0xff);
#else
    W2p[t] = f32_to_fp8_sw(v);
#endif
}

// h: [node(64)][hid(512)] fp8, XOR-swizzled 8B slots: byte = node*512 + ((sub8 ^ (node&15))<<3) + o4
// xself: [64][40] f32, 16B chunks 0..7 stored at chunk ^ (node&7); chunks 8,9 linear.
// Register discipline: 64-reg cap at 8 waves/EU (unified VGPR+AGPR file).
// Max 16 AGPRs live (sequential hid-tile halves); nothing else crosses barriers.
__global__ __launch_bounds__(NTHR, 8) void step_mfma(
    const float* __restrict__ xsrc, float* __restrict__ xdst,
    const int* __restrict__ index,
    const unsigned short* __restrict__ W1p, const float* __restrict__ b1,
    const unsigned char* __restrict__ W2p, const float* __restrict__ b2)
{
    __shared__ alignas(16) unsigned char smem[LDS_TOT];
    unsigned short* z = (unsigned short*)smem;          // [64][ZS] bf16, dies after barrier 2
    unsigned char*  h = smem + H_OFF;                   // [64][512] fp8 swizzled
    float* xself = (float*)(smem + XS_OFF);             // [64][40] f32 self rows (chunk-swizzled)
    float* stg   = (float*)smem;                        // GEMM2 kh=1 partials (overlay z)

    const int tid = threadIdx.x;
    const int w   = tid >> 6;        // 0..15
    const int ln  = tid & 63;
    const int nl  = ln & 15;
    const int q   = ln >> 4;
    const int n0  = blockIdx.x * TM;
    const int b   = blockIdx.y;
    const size_t xbase = (size_t)b * NN * DDIM;

    // GEMM2 wave roles
    const int nt2 = w & 3;           // node tile
    const int jt  = (w >> 2) & 1;    // output j tile
    const int kh  = w >> 3;          // K half

    // ---- Phase 1: gather -> z bf16 (64 nodes x 4 nbrs x 10 float4 = 2560 tasks);
    //      k==0 (self row) also stashed f32 (chunk-swizzled) in xself for the epilogue ----
    if (n0 + TM <= NN) {   // fast path (640 of 641 blocks): 3 independent load chains up front
        const int e0 = tid, e1 = tid + NTHR, e2 = tid + 2 * NTHR;
        const bool has2 = (e2 < TM * 40);
        int m0 = e0 / 40, r0 = e0 - m0 * 40, k0 = r0 / 10, q0 = r0 - k0 * 10;
        int m1 = e1 / 40, r1 = e1 - m1 * 40, k1 = r1 / 10, q1 = r1 - k1 * 10;
        int m2 = e2 / 40, r2 = e2 - m2 * 40, k2 = r2 / 10, q2 = r2 - k2 * 10;
        int nb0 = index[(n0 + m0) * 4 + k0];
        int nb1 = index[(n0 + m1) * 4 + k1];
        int nb2 = has2 ? index[(n0 + m2) * 4 + k2] : nb1;
        float4 v0 = ((const float4*)(xsrc + xbase + (size_t)nb0 * DDIM))[q0];
        float4 v1 = ((const float4*)(xsrc + xbase + (size_t)nb1 * DDIM))[q1];
        float4 v2 = ((const float4*)(xsrc + xbase + (size_t)nb2 * DDIM))[has2 ? q2 : q1];
        *(uint2*)(z + m0 * ZS + k0 * 40 + q0 * 4) =
            make_uint2(cvt_pk_bf16(v0.x, v0.y), cvt_pk_bf16(v0.z, v0.w));
        if (k0 == 0) { int c = (q0 < 8) ? (q0 ^ (m0 & 7)) : q0;
                       *(float4*)(xself + m0 * 40 + c * 4) = v0; }
        *(uint2*)(z + m1 * ZS + k1 * 40 + q1 * 4) =
            make_uint2(cvt_pk_bf16(v1.x, v1.y), cvt_pk_bf16(v1.z, v1.w));
        if (k1 == 0) { int c = (q1 < 8) ? (q1 ^ (m1 & 7)) : q1;
                       *(float4*)(xself + m1 * 40 + c * 4) = v1; }
        if (has2) {
            *(uint2*)(z + m2 * ZS + k2 * 40 + q2 * 4) =
                make_uint2(cvt_pk_bf16(v2.x, v2.y), cvt_pk_bf16(v2.z, v2.w));
            if (k2 == 0) { int c = (q2 < 8) ? (q2 ^ (m2 & 7)) : q2;
                           *(float4*)(xself + m2 * 40 + c * 4) = v2; }
        }
    } else {
        for (int e = tid; e < TM * 4 * 10; e += NTHR) {
            int m = e / 40, r = e - m * 40;
            int k = r / 10, qq = r - k * 10;
            unsigned lo = 0, hi = 0;
            int n = n0 + m;
            float4 v = make_float4(0.f, 0.f, 0.f, 0.f);
            if (n < NN) {
                int nb = index[n * 4 + k];
                v = ((const float4*)(xsrc + xbase + (size_t)nb * DDIM))[qq];
                lo = cvt_pk_bf16(v.x, v.y);
                hi = cvt_pk_bf16(v.z, v.w);
            }
            *(uint2*)(z + m * ZS + k * 40 + qq * 4) = make_uint2(lo, hi);
            if (k == 0) {
                int c = (qq < 8) ? (qq ^ (m & 7)) : qq;
                *(float4*)(xself + m * 40 + c * 4) = v;
            }
        }
    }
    __syncthreads();   // barrier 1: z + xself ready

    // ---- Phase 2+3, half A (hid tile w*2): GEMM1 -> gelu -> h. acc dies before half B. ----
    const unsigned short* w1b = W1p + ((size_t)(w * 2) * 5) * 512 + ln * 8;
    {
        f32x4 acc[4];
        float4 bv = *(const float4*)(b1 + (w * 2) * 16 + q * 4);
        f32x4 a0; a0[0] = bv.x; a0[1] = bv.y; a0[2] = bv.z; a0[3] = bv.w;
        #pragma unroll
        for (int nt = 0; nt < 4; ++nt) acc[nt] = a0;
        gemm1_half(w1b, z, acc, nl, q);
        gelu_pack_store(h, acc, (w * 2) * 16 + q * 4, nl, q);
    }

    // ---- Phase 2+3, half B (hid tile w*2+1) ----
    f32x4 acc[4];
    {
        float4 bv = *(const float4*)(b1 + (w * 2 + 1) * 16 + q * 4);
        f32x4 a0; a0[0] = bv.x; a0[1] = bv.y; a0[2] = bv.z; a0[3] = bv.w;
        #pragma unroll
        for (int nt = 0; nt < 4; ++nt) acc[nt] = a0;
        gemm1_half(w1b + 5 * 512, z, acc, nl, q);
    }

    // prefetch this wave's 8 W2p fragments + b2 (L2 latency hidden under half-B gelu;
    // held across barrier 2 -- affordable at 16-AGPR max)
    long long wf[8];
    #pragma unroll
    for (int kk = 0; kk < 8; ++kk)
        __builtin_memcpy(&wf[kk], W2p + (size_t)(((jt * 16 + kh * 8 + kk) * 64 + ln) * 8), 8);
    float4 bv2 = make_float4(0.f, 0.f, 0.f, 0.f);
    if (kh == 0) bv2 = *(const float4*)(b2 + jt * 16 + q * 4);

    gelu_pack_store(h, acc, (w * 2 + 1) * 16 + q * 4, nl, q);
    __syncthreads();   // barrier 2: all h written; z dead from here

    // ---- Phase 4: GEMM2 16-wave (kh x jt x nt), 8 MFMA/wave, prefetched A-frags ----
    const int hrow = nt2 * 16 + nl;
    f32x4 acc2;
    acc2[0] = bv2.x; acc2[1] = bv2.y; acc2[2] = bv2.z; acc2[3] = bv2.w;
    #pragma unroll
    for (int kk = 0; kk < 8; ++kk) {
        int kg = kh * 8 + kk;
        long long bfr;
        __builtin_memcpy(&bfr, h + hrow * 512 + (((kg * 4 + q) ^ (hrow & 15)) << 3), 8);
        acc2 = __builtin_amdgcn_mfma_f32_16x16x32_fp8_fp8(wf[kk], bfr, acc2, 0, 0, 0);
    }
    if (kh == 1)   // stage partial in stg (overlay z; z dead since barrier 2)
        *(f32x4*)(stg + ((w - 8) * 64 + ln) * 4) = acc2;
    __syncthreads();   // barrier 3: partials staged

    // ---- Phase 4b (kh==0 waves): combine partials, fmaf update into xself (in LDS) ----
    if (kh == 0) {
        f32x4 p = *(const f32x4*)(stg + (w * 64 + ln) * 4);
        int c = (jt * 4 + q) ^ (hrow & 7);
        float* xp = xself + hrow * 40 + c * 4;
        float4 s = *(const float4*)xp;
        s.x = fmaf(STEPSZ, acc2[0] + p[0], s.x);
        s.y = fmaf(STEPSZ, acc2[1] + p[1], s.y);
        s.z = fmaf(STEPSZ, acc2[2] + p[2], s.z);
        s.w = fmaf(STEPSZ, acc2[3] + p[3], s.w);
        *(float4*)xp = s;
    }
    __syncthreads();   // barrier 4: xself updated

    // ---- Phase 5: coalesced full-row epilogue, 640 float4 tasks ----
    if (tid < TM * 10) {
        int m = tid / 10, p = tid - m * 10;
        int n = n0 + m;
        if (n < NN) {
            int c = (p < 8) ? (p ^ (m & 7)) : p;
            float4 v = *(const float4*)(xself + m * 40 + c * 4);
            *(float4*)(xdst + xbase + (size_t)n * DDIM + p * 4) = v;
        }
    }
}

// ================= fallback f32 path (used only if ws too small) =================
constexpr int FTM = 16;
__device__ __forceinline__ float gelu_f(float x) {
    float t = x * fmaf(-0.10294357f, x * x, -2.3022077f);
    return x * __builtin_amdgcn_rcpf(1.0f + exp2_hw(t));
}
__global__ __launch_bounds__(256) void step_f32(
    const float* __restrict__ xsrc, float* __restrict__ xdst,
    const int* __restrict__ index,
    const float* __restrict__ W1, const float* __restrict__ b1,
    const float* __restrict__ W2, const float* __restrict__ b2)
{
    __shared__ float z_lds[FTM][160];
    __shared__ float h_lds[FTM][HH];
    __shared__ float fz_lds[FTM][DDYN];
    const int tid = threadIdx.x, tile = blockIdx.x, b = blockIdx.y;
    const int n0 = tile * FTM;
    const int nvalid = min(FTM, NN - n0);
    for (int e = tid; e < FTM * 4 * 10; e += 256) {
        int m = e / 40, r = e % 40, k = r / 10, qq = r % 10;
        float4 v = make_float4(0.f, 0.f, 0.f, 0.f);
        int n = n0 + m;
        if (n < NN) {
            int nb = index[n * 4 + k];
            v = ((const float4*)(xsrc + ((size_t)b * NN + nb) * DDIM))[qq];
        }
        ((float4*)&z_lds[m][k * DDIM])[qq] = v;
    }
    __syncthreads();
    const int c0 = 2 * tid;
    float2 acc[FTM];
    {
        float bx = b1[c0], by = b1[c0 + 1];
        #pragma unroll
        for (int m = 0; m < FTM; ++m) { acc[m].x = bx; acc[m].y = by; }
    }
    for (int kd = 0; kd < 160; kd += 4) {
        float2 w0 = *(const float2*)(W1 + (size_t)(kd + 0) * HH + c0);
        float2 w1 = *(const float2*)(W1 + (size_t)(kd + 1) * HH + c0);
        float2 w2 = *(const float2*)(W1 + (size_t)(kd + 2) * HH + c0);
        float2 w3 = *(const float2*)(W1 + (size_t)(kd + 3) * HH + c0);
        #pragma unroll
        for (int m = 0; m < FTM; ++m) {
            float4 zv = *(const float4*)&z_lds[m][kd];
            acc[m].x = fmaf(zv.x, w0.x, acc[m].x); acc[m].y = fmaf(zv.x, w0.y, acc[m].y);
            acc[m].x = fmaf(zv.y, w1.x, acc[m].x); acc[m].y = fmaf(zv.y, w1.y, acc[m].y);
            acc[m].x = fmaf(zv.z, w2.x, acc[m].x); acc[m].y = fmaf(zv.z, w2.y, acc[m].y);
            acc[m].x = fmaf(zv.w, w3.x, acc[m].x); acc[m].y = fmaf(zv.w, w3.y, acc[m].y);
        }
    }
    #pragma unroll
    for (int m = 0; m < FTM; ++m) {
        h_lds[m][c0]     = gelu_f(acc[m].x);
        h_lds[m][c0 + 1] = gelu_f(acc[m].y);
    }
    __syncthreads();
    {
        const int j = tid & 31, mg = tid >> 5;
        float a0 = b2[j], a1 = a0;
        for (int c = 0; c < HH; c += 4) {
            float wa = W2[(size_t)(c + 0) * DDYN + j];
            float wb = W2[(size_t)(c + 1) * DDYN + j];
            float wc = W2[(size_t)(c + 2) * DDYN + j];
            float wd = W2[(size_t)(c + 3) * DDYN + j];
            float4 h0 = *(const float4*)&h_lds[mg][c];
            float4 h1 = *(const float4*)&h_lds[mg + 8][c];
            a0 = fmaf(h0.x, wa, a0); a0 = fmaf(h0.y, wb, a0);
            a0 = fmaf(h0.z, wc, a0); a0 = fmaf(h0.w, wd, a0);
            a1 = fmaf(h1.x, wa, a1); a1 = fmaf(h1.y, wb, a1);
            a1 = fmaf(h1.z, wc, a1); a1 = fmaf(h1.w, wd, a1);
        }
        fz_lds[mg][j] = a0; fz_lds[mg + 8][j] = a1;
    }
    __syncthreads();
    const size_t base = ((size_t)b * NN + n0) * (size_t)DDIM;
    for (int e = tid; e < nvalid * DDIM; e += 256) {
        int m = e / DDIM, d = e % DDIM;
        float v = xsrc[base + e];
        if (d < DDYN) v = fmaf(STEPSZ, fz_lds[m][d], v);
        xdst[base + e] = v;
    }
}

extern "C" void kernel_launch(void* const* d_in, const int* in_sizes, int n_in,
                              void* d_out, int out_size, void* d_ws, size_t ws_size,
                              hipStream_t stream) {
    const float* x   = (const float*)d_in[0];
    const int*   idx = (const int*)  d_in[1];
    const float* W1  = (const float*)d_in[2];
    const float* b1  = (const float*)d_in[3];
    const float* W2  = (const float*)d_in[4];
    const float* b2  = (const float*)d_in[5];
    float* out  = (float*)d_out;
    float* xbuf = (float*)d_ws;

    const size_t need = X_BYTES + (size_t)W1P_ELEMS * 2 + W2P_BYTES;
    if (ws_size >= need) {
        unsigned short* W1p = (unsigned short*)((char*)d_ws + X_BYTES);
        unsigned char*  W2p = (unsigned char*)(W1p + W1P_ELEMS);
        pack_w1<<<(W1P_ELEMS + 255) / 256, 256, 0, stream>>>(W1, W1p);
        pack_w2_fp8<<<(W2P_BYTES + 255) / 256, 256, 0, stream>>>(W2, W2p);
        dim3 grid((NN + TM - 1) / TM, BB), block(NTHR);
        step_mfma<<<grid, block, 0, stream>>>(x,    xbuf, idx, W1p, b1, W2p, b2);
        step_mfma<<<grid, block, 0, stream>>>(xbuf, out,  idx, W1p, b1, W2p, b2);
        step_mfma<<<grid, block, 0, stream>>>(out,  xbuf, idx, W1p, b1, W2p, b2);
        step_mfma<<<grid, block, 0, stream>>>(xbuf, out,  idx, W1p, b1, W2p, b2);
    } else {
        dim3 grid((NN + FTM - 1) / FTM, BB), block(256);
        step_f32<<<grid, block, 0, stream>>>(x,    xbuf, idx, W1, b1, W2, b2);
        step_f32<<<grid, block, 0, stream>>>(xbuf, out,  idx, W1, b1, W2, b2);
        step_f32<<<grid, block, 0, stream>>>(out,  xbuf, idx, W1, b1, W2, b2);
        step_f32<<<grid, block, 0, stream>>>(xbuf, out,  idx, W1, b1, W2, b2);
    }
}